// Round 6
// baseline (435.924 us; speedup 1.0000x reference)
//
#include <hip/hip_runtime.h>

#define NSTEP 730
#define NGRID 1000
#define NPAR  13
#define PRECS 1e-5f

// parameters (NSTEP, NGRID, 13, MU=8): idx(t,g,i,m) = t*104000 + g*104 + i*8 + m
#define PAR_TSTRIDE 104000u
#define PAR_GSTRIDE 104u
// x (NSTEP, NGRID, 3): idx(t,g,c) = t*3000 + g*3 + c
#define X_TSTRIDE 3000u

#define G5    5                  // steps per group (fast path)
#define NGRP5 146                // 730/5 groups

#define GSTEPS 10                // legacy generic path group size
#define NGROUP 73

constexpr float LB_[NPAR] = {1.0f, 50.0f, 0.05f, 0.01f, 0.001f, 0.2f, 0.0f,
                             0.0f, -2.5f, 0.5f, 0.0f, 0.0f, 0.3f};
constexpr float UB_[NPAR] = {6.0f, 1000.0f, 0.9f, 0.5f, 0.2f, 1.0f, 10.0f,
                             100.0f, 2.5f, 10.0f, 0.1f, 0.2f, 5.0f};

__device__ __forceinline__ float fast_rcp(float x)  { return __builtin_amdgcn_rcpf(x); }
__device__ __forceinline__ float fast_exp2(float x) { return __builtin_amdgcn_exp2f(x); }
__device__ __forceinline__ float fast_log2(float x) { return __builtin_amdgcn_logf(x); }

__device__ __forceinline__ int mod13(int v) {
    int r = v % NPAR;
    if (r < 0) r += NPAR;
    return r;
}

// ---- 8-lane (mu) sum stages.
template <int CTRL>
__device__ __forceinline__ float dpp_xadd(float v) {
    int r = __builtin_amdgcn_update_dpp(0, __float_as_int(v), CTRL, 0xF, 0xF, true);
    return v + __int_as_float(r);
}
// Legacy (verified) version with ds_swizzle xor4 — used by generic paths.
__device__ __forceinline__ float mu8_sum(float v) {
    v = dpp_xadd<0xB1>(v);   // lane ^= 1
    v = dpp_xadd<0x4E>(v);   // lane ^= 2
    int s = __builtin_amdgcn_ds_swizzle(__float_as_int(v), 0x101F); // lane ^= 4
    return v + __int_as_float(s);
}
// Pure-DPP version (R2-harness-verified): after xor1/xor2 all 4 lanes of a
// quad hold bitwise-equal partial sums; row_half_mirror pairs with the other
// quad of the 8-group -> bitwise-identical total. No LDS pipe usage.
__device__ __forceinline__ float mu8_sum_dpp(float v) {
    v = dpp_xadd<0xB1>(v);    // lane ^= 1
    v = dpp_xadd<0x4E>(v);    // lane ^= 2
    v = dpp_xadd<0x141>(v);   // row_half_mirror: cross-quad within 8-group
    return v;
}

// One HBV step (legacy helper for generic paths).
__device__ __forceinline__ float hbv_step_core(
    float P_, float T_, float ET_,
    float BETA, float FC, float K0, float K1, float K2,
    float PERCc, float UZL, float TT, float CFMAX, float CFR, float CWH,
    float BETAET, float rcpFC, float rcpLPFC,
    float& SP, float& MW, float& SM, float& SUZ, float& SLZ)
{
    float dT    = T_ - TT;
    float RAIN  = (T_ >= TT) ? P_ : 0.f;
    float SNOW  = P_ - RAIN;
    SP += SNOW;
    float cm    = CFMAX * dT;
    float melt  = fminf(fmaxf(cm, 0.f), SP);
    MW += melt; SP -= melt;
    float refr  = fminf(fmaxf(-CFR * cm, 0.f), MW);
    SP += refr; MW -= refr;
    float tosoil = fmaxf(MW - CWH * SP, 0.f);
    MW -= tosoil;
    float soilw  = fminf(fast_exp2(BETA * fast_log2(SM * rcpFC)), 1.f);
    float rt     = RAIN + tosoil;
    float rech   = rt * soilw;
    SM += rt - rech;
    float excess = fmaxf(SM - FC, 0.f);
    SM -= excess;
    float evapf  = fminf(fast_exp2(BETAET * fast_log2(SM * rcpLPFC)), 1.f);
    float ETact  = fminf(SM, ET_ * evapf);
    SM = fmaxf(SM - ETact, PRECS);
    SUZ += rech + excess;
    float PERC = fminf(SUZ, PERCc);
    SUZ -= PERC;
    float Q0 = K0 * fmaxf(SUZ - UZL, 0.f);
    SUZ -= Q0;
    float Q1 = K1 * SUZ;
    SUZ -= Q1;
    SLZ += PERC;
    float Q2 = K2 * SLZ;
    SLZ -= Q2;
    return Q0 + Q1 + Q2;
}

// ---- Generic NTD=2 single-wave body (verified fallback for idx != {12,0}).
__device__ void hbv_generic2(
    const float* __restrict__ x, const float* __restrict__ par,
    int staind, int idx0, int idx1, float* __restrict__ out, int g, int m)
{
    const unsigned cpar = (unsigned)g * PAR_GSTRIDE + (unsigned)m;
    const unsigned g3   = (unsigned)g * 3u;

    float lb0 = 0.f, dv0 = 0.f, lb1 = 0.f, dv1 = 0.f;
    float sel0[NPAR], sel1[NPAR];
#pragma unroll
    for (int i = 0; i < NPAR; ++i) {
        sel0[i] = (idx0 == i) ? 1.f : 0.f;
        sel1[i] = (idx1 == i && idx1 != idx0) ? 1.f : 0.f;
        if (idx0 == i) { lb0 = LB_[i]; dv0 = UB_[i] - LB_[i]; }
        if (idx1 == i) { lb1 = LB_[i]; dv1 = UB_[i] - LB_[i]; }
    }
    const unsigned off0 = (unsigned)idx0 * 8u, off1 = (unsigned)idx1 * 8u;

    float basep[NPAR];
    const unsigned sbase = (unsigned)staind * PAR_TSTRIDE + cpar;
#pragma unroll
    for (int i = 0; i < NPAR; ++i) {
        float fxv = fmaf(par[sbase + (unsigned)i * 8u], UB_[i] - LB_[i], LB_[i]);
        basep[i] = fxv * (1.f - sel0[i] - sel1[i]);
    }

    float bP[2][GSTEPS], bT[2][GSTEPS], bEv[2][GSTEPS];
    float bS0[2][GSTEPS], bS1[2][GSTEPS];
    float SP = 0.001f, MW = 0.001f, SM = 0.001f, SUZ = 0.001f, SLZ = 0.001f;

    auto load = [&](int b, int t0) {
#pragma unroll
        for (int j = 0; j < GSTEPS; ++j) {
            unsigned t  = (unsigned)(t0 + j);
            unsigned xo = t * X_TSTRIDE + g3;
            bP[b][j]  = x[xo];
            bT[b][j]  = x[xo + 1u];
            bEv[b][j] = x[xo + 2u];
            unsigned po = t * PAR_TSTRIDE + cpar;
            bS0[b][j] = par[po + off0];
            bS1[b][j] = par[po + off1];
        }
    };
    auto compute = [&](int b, int t0) {
        float ql[GSTEPS];
#pragma unroll
        for (int j = 0; j < GSTEPS; ++j) {
            float sv0 = fmaf(bS0[b][j], dv0, lb0);
            float sv1 = fmaf(bS1[b][j], dv1, lb1);
            float pr[NPAR];
#pragma unroll
            for (int i = 0; i < NPAR; ++i)
                pr[i] = fmaf(sel1[i], sv1, fmaf(sel0[i], sv0, basep[i]));
            float rcpFC   = fast_rcp(pr[1]);
            float rcpLPFC = fast_rcp(pr[5] * pr[1]);
            ql[j] = hbv_step_core(bP[b][j], bT[b][j], bEv[b][j],
                                  pr[0], pr[1], pr[2], pr[3], pr[4], pr[6],
                                  pr[7], pr[8], pr[9], pr[10], pr[11], pr[12],
                                  rcpFC, rcpLPFC, SP, MW, SM, SUZ, SLZ);
        }
#pragma unroll
        for (int j = 0; j < GSTEPS; ++j) {
            float s = mu8_sum(ql[j]);
            if (m == 0)
                out[(unsigned)(t0 + j) * (unsigned)NGRID + (unsigned)g] = s * 0.125f;
        }
    };

    load(0, 0);
    for (int gp = 0; gp < NGROUP; gp += 2) {
        if (gp + 1 < NGROUP) load(1, (gp + 1) * GSTEPS);
        compute(0, gp * GSTEPS);
        if (gp + 2 < NGROUP) load(0, (gp + 2) * GSTEPS);
        if (gp + 1 < NGROUP) compute(1, (gp + 1) * GSTEPS);
    }
}

// ==== Fast single-wave kernel, tuned for the vmcnt(<=63) window.
// 125 blocks x 64 threads, one chain per lane. No LDS, no barriers.
// G5 x 3 VGPR buffers, prefetch distance = 2 groups:
//   loads/group = 5 steps x (1 float3 + 2 scalar) <= 25 VMEM
//   max outstanding = 2 groups = 50  < 63  -> compiler's s_waitcnt vmcnt(N)
//   never clamps, so group-k waits cost ~0 (issued 2 full groups earlier).
// Chain arithmetic bitwise-identical to the verified R1 consumer; reduction
// is the R2-harness-verified pure-DPP mu8 sum.
__global__ __launch_bounds__(64, 1) void hbv_fast2(
    const float* __restrict__ x, const float* __restrict__ par,
    const int* __restrict__ staind_p, const int* __restrict__ tdlst_p,
    float* __restrict__ out)
{
    const int lane  = threadIdx.x;              // 0..63
    const int chain = blockIdx.x * 64 + lane;   // 125*64 = 8000 chains exactly
    const int g = chain >> 3;
    const int m = chain & 7;

    const int staind = __builtin_amdgcn_readfirstlane(staind_p[0]);
    const int idx0   = __builtin_amdgcn_readfirstlane(mod13(tdlst_p[0] - 1));
    const int idx1   = __builtin_amdgcn_readfirstlane(mod13(tdlst_p[1] - 1));

    if (!(idx0 == 12 && idx1 == 0)) {           // grid-uniform branch
        hbv_generic2(x, par, staind, idx0, idx1, out, g, m);
        return;
    }

    const unsigned cpar = (unsigned)g * PAR_GSTRIDE + (unsigned)m;
    const unsigned g3   = (unsigned)g * 3u;

    // staind-row params, scaled.
    float fx[NPAR];
    const unsigned sbase = (unsigned)staind * PAR_TSTRIDE + cpar;
#pragma unroll
    for (int i = 0; i < NPAR; ++i)
        fx[i] = fmaf(par[sbase + (unsigned)i * 8u], UB_[i] - LB_[i], LB_[i]);

    const float FC = fx[1], K0 = fx[2], K1 = fx[3], K2 = fx[4],
                PERCc = fx[6], UZL = fx[7], TT = fx[8], CFMAX = fx[9],
                CWH = fx[11];
    const float CC       = fx[10] * fx[9];           // CFR * CFMAX
    const float rcpFC    = fast_rcp(fx[1]);
    const float rcpLPFC  = fast_rcp(fx[5] * fx[1]);
    const float l2rcpFC  = fast_log2(rcpFC);
    const float l2rcpLPF = fast_log2(rcpLPFC);
    constexpr float lbB = LB_[0],  dvB = UB_[0]  - LB_[0];
    constexpr float lbE = LB_[12], dvE = UB_[12] - LB_[12];

    // 3 buffers x 5 steps x 5 values = 75 VGPRs.
    float vP[3][G5], vT[3][G5], vE[3][G5], v0[3][G5], v1[3][G5];

    float SP = 0.001f, MW = 0.001f, SM = 0.001f, SUZ = 0.001f, SLZ = 0.001f;

// B must be a LITERAL (0/1/2) so all array indexing is compile-time (no
// scratch). float3 is 12B/align-4 -> dwordx3 (or 3 dwords) per step.
#define GLOAD(B, grp)                                                      \
    {                                                                      \
        const int t0_ = (grp) * G5;                                        \
        const float* xp_ = x   + (unsigned)t0_ * X_TSTRIDE   + g3;         \
        const float* pp_ = par + (unsigned)t0_ * PAR_TSTRIDE + cpar;       \
        _Pragma("unroll")                                                  \
        for (int j = 0; j < G5; ++j) {                                     \
            float3 xv_ = *reinterpret_cast<const float3*>(xp_);            \
            vP[B][j] = xv_.x; vT[B][j] = xv_.y; vE[B][j] = xv_.z;          \
            v1[B][j] = pp_[0];    /* param 0  raw (BETA)   */              \
            v0[B][j] = pp_[96];   /* param 12 raw (BETAET) */              \
            xp_ += X_TSTRIDE;                                              \
            pp_ += PAR_TSTRIDE;                                            \
        }                                                                  \
    }

#define COMPUTE(B, grp)                                                    \
    {                                                                      \
        const int t0_ = (grp) * G5;                                        \
        _Pragma("unroll")                                                  \
        for (int j = 0; j < G5; ++j) {                                     \
            float Pj = vP[B][j], Tj = vT[B][j], ET = vE[B][j];             \
            float dT     = Tj - TT;                                        \
            float RAIN   = (dT >= 0.f) ? Pj : 0.f;                         \
            float SNOW   = Pj - RAIN;                                      \
            float MAXCM  = fmaxf(CFMAX * dT, 0.f);                         \
            float MAXRF  = fmaxf(-CC * dT, 0.f);                           \
            float BETAET = fmaf(v0[B][j], dvE, lbE);                       \
            float BETA   = fmaf(v1[B][j], dvB, lbB);                       \
            float bbc    = BETA * l2rcpFC;                                 \
            float ebc    = BETAET * l2rcpLPF;                              \
            SP += SNOW;                                                    \
            float melt = fminf(MAXCM, SP);                                 \
            MW += melt; SP -= melt;                                        \
            float refr = fminf(MAXRF, MW);                                 \
            SP += refr; MW -= refr;                                        \
            float tosoil = fmaxf(fmaf(-CWH, SP, MW), 0.f);                 \
            MW -= tosoil;                                                  \
            float rt    = RAIN + tosoil;                                   \
            float soilw = fast_exp2(fmaf(BETA, fast_log2(SM), bbc));       \
            float rech  = rt * soilw;                                      \
            float SM_mid = SM + rt - rech;                                 \
            float SM_ae  = fminf(SM_mid, FC);                              \
            float excess = SM_mid - SM_ae;                                 \
            float evapf  = fminf(                                          \
                fast_exp2(fmaf(BETAET, fast_log2(SM_ae), ebc)), 1.f);      \
            SM = fmaxf(fmaf(-ET, evapf, SM_ae), PRECS);                    \
            SUZ += rech + excess;                                          \
            float PERC = fminf(SUZ, PERCc);                                \
            float SUZp = SUZ - PERC;                                       \
            float Q0   = K0 * fmaxf(SUZp - UZL, 0.f);                      \
            float SUZq = SUZp - Q0;                                        \
            float Q1   = K1 * SUZq;                                        \
            SUZ = SUZq - Q1;                                               \
            SLZ += PERC;                                                   \
            float Q2 = K2 * SLZ;                                           \
            SLZ -= Q2;                                                     \
            float q = (Q0 + Q1) + Q2;                                      \
            float s = mu8_sum_dpp(q);                                      \
            if (m == 0)                                                    \
                out[(unsigned)(t0_ + j) * (unsigned)NGRID + (unsigned)g]   \
                    = s * 0.125f;                                          \
        }                                                                  \
    }

    // Guard-free pipeline: group g lives in buffer g % 3; prefetch distance 2.
    // 146 groups = 2 (prologue) + 48*3 (steady) - 2 ... : loop covers k=0..143
    // with GLOAD(k+2) <= 145; tail computes 144, 145 (already loaded).
    GLOAD(0, 0);
    GLOAD(1, 1);
    int k = 0;
    for (int t = 0; t < 48; ++t) {
        GLOAD(2, k + 2); COMPUTE(0, k); ++k;
        GLOAD(0, k + 2); COMPUTE(1, k); ++k;
        GLOAD(1, k + 2); COMPUTE(2, k); ++k;
    }
    COMPUTE(0, 144);
    COMPUTE(1, 145);
#undef GLOAD
#undef COMPUTE
}

// ---- Fallback kernel for n_td != 2 (unchanged, verified).
__global__ __launch_bounds__(64, 1) void hbv_scan_generic(
    const float* __restrict__ x, const float* __restrict__ par,
    const int* __restrict__ staind_p, const int* __restrict__ tdlst_p,
    int n_td, float* __restrict__ out)
{
    const int tid = blockIdx.x * 64 + threadIdx.x;
    const int g   = tid >> 3;
    const int m   = tid & 7;
    if (g >= NGRID) return;

    const int staind    = staind_p[0];
    const unsigned cpar = (unsigned)g * PAR_GSTRIDE + (unsigned)m;
    const unsigned g3   = (unsigned)g * 3u;

    unsigned off[NPAR], st[NPAR];
#pragma unroll
    for (int i = 0; i < NPAR; ++i) {
        bool vr = false;
        for (int j = 0; j < n_td; ++j)
            if (mod13(tdlst_p[j] - 1) == i) vr = true;
        off[i] = (vr ? 0u : (unsigned)staind * PAR_TSTRIDE) + cpar + (unsigned)i * 8u;
        st[i]  = vr ? PAR_TSTRIDE : 0u;
    }

    float SP = 0.001f, MW = 0.001f, SM = 0.001f, SUZ = 0.001f, SLZ = 0.001f;
    for (int t = 0; t < NSTEP; ++t) {
        unsigned xo = (unsigned)t * X_TSTRIDE + g3;
        float P_ = x[xo], T_ = x[xo + 1u], E_ = x[xo + 2u];
        float pr[NPAR];
#pragma unroll
        for (int i = 0; i < NPAR; ++i) {
            pr[i] = fmaf(par[off[i]], UB_[i] - LB_[i], LB_[i]);
            off[i] += st[i];
        }
        float rcpFC   = fast_rcp(pr[1]);
        float rcpLPFC = fast_rcp(pr[5] * pr[1]);
        float q = hbv_step_core(P_, T_, E_, pr[0], pr[1], pr[2], pr[3], pr[4],
                                pr[6], pr[7], pr[8], pr[9], pr[10], pr[11],
                                pr[12], rcpFC, rcpLPFC, SP, MW, SM, SUZ, SLZ);
        float s = mu8_sum(q);
        if (m == 0) out[(unsigned)t * (unsigned)NGRID + (unsigned)g] = s * 0.125f;
    }
}

extern "C" void kernel_launch(void* const* d_in, const int* in_sizes, int n_in,
                              void* d_out, int out_size, void* d_ws, size_t ws_size,
                              hipStream_t stream) {
    const float* x      = (const float*)d_in[0];
    const float* par    = (const float*)d_in[1];
    const int*   staind = (const int*)d_in[2];
    const int*   tdlst  = (const int*)d_in[3];
    float*       out    = (float*)d_out;
    const int n_td = in_sizes[3];

    if (n_td == 2) {
        hbv_fast2<<<125, 64, 0, stream>>>(x, par, staind, tdlst, out);
    } else {
        hbv_scan_generic<<<125, 64, 0, stream>>>(x, par, staind, tdlst,
                                                 n_td, out);
    }
}